// Round 2
// baseline (3555.199 us; speedup 1.0000x reference)
//
#include <hip/hip_runtime.h>

// Problem constants (fixed by setup_inputs)
#define BB     4
#define NQS    4096
#define NVS    9216
#define E_DIM  768
#define NHEAD  8
#define NPTS   4
#define HDIM   96
#define HFEAT  96
#define WFEAT  96

// ---------------------------------------------------------------------------
// Row stats for LayerNorm: one block per row of 768 -> (mean, rstd)
// ---------------------------------------------------------------------------
__global__ void row_stats_kernel(const float* __restrict__ x, float* __restrict__ stats) {
    const int row = blockIdx.x;
    const int t = threadIdx.x;
    const float* xr = x + (size_t)row * E_DIM;

    float v0 = xr[t];
    float v1 = xr[t + 256];
    float v2 = xr[t + 512];
    float s1 = v0 + v1 + v2;
    float s2 = v0 * v0 + v1 * v1 + v2 * v2;

    __shared__ float sh[8];
    #pragma unroll
    for (int o = 32; o > 0; o >>= 1) {
        s1 += __shfl_down(s1, o, 64);
        s2 += __shfl_down(s2, o, 64);
    }
    const int lane = t & 63, wv = t >> 6;
    if (lane == 0) { sh[wv * 2] = s1; sh[wv * 2 + 1] = s2; }
    __syncthreads();
    if (t == 0) {
        float a = 0.f, b = 0.f;
        #pragma unroll
        for (int i = 0; i < 4; i++) { a += sh[i * 2]; b += sh[i * 2 + 1]; }
        float mean = a * (1.0f / E_DIM);
        float var = b * (1.0f / E_DIM) - mean * mean;
        stats[row * 2 + 0] = mean;
        stats[row * 2 + 1] = rsqrtf(var + 1e-6f);
    }
}

// ---------------------------------------------------------------------------
// Tiled SIMT GEMM with fused LayerNorm on A:
//   C[M,N] = LN(X)[M,K] @ W[K,N] + bias[N]
// LN(X)[m,k] = (X[m,k]-mu_m)*rs_m*lnw[k] + lnb[k]
// BM=BN=128, BK=16, 256 threads, 8x8 per thread. N guarded.
// ---------------------------------------------------------------------------
__global__ void gemm_ln_kernel(const float* __restrict__ X, const float* __restrict__ stats,
                               const float* __restrict__ lnw, const float* __restrict__ lnb,
                               const float* __restrict__ W, const float* __restrict__ bias,
                               float* __restrict__ C, int M, int N, int K) {
    const int BM = 128, BN = 128, BK = 16;
    __shared__ float As[BK][BM];
    __shared__ float Bs[BK][BN];

    const int tid = threadIdx.x;
    const int bm = blockIdx.y * BM;
    const int bn = blockIdx.x * BN;
    const int tr = tid >> 4;
    const int tc = tid & 15;

    float acc[8][8];
    #pragma unroll
    for (int i = 0; i < 8; i++)
        #pragma unroll
        for (int j = 0; j < 8; j++) acc[i][j] = 0.f;

    for (int k0 = 0; k0 < K; k0 += BK) {
        #pragma unroll
        for (int i = 0; i < 8; i++) {
            int idx = tid + i * 256;
            int m = idx >> 4, kk = idx & 15;
            int gm = bm + m, gk = k0 + kk;
            float xv = X[(size_t)gm * K + gk];
            float mu = stats[gm * 2 + 0], rs = stats[gm * 2 + 1];
            As[kk][m] = (xv - mu) * rs * lnw[gk] + lnb[gk];
        }
        #pragma unroll
        for (int i = 0; i < 8; i++) {
            int idx = tid + i * 256;
            int kk = idx >> 7, n = idx & 127;
            float v = 0.f;
            if (bn + n < N) v = W[(size_t)(k0 + kk) * N + bn + n];
            Bs[kk][n] = v;
        }
        __syncthreads();
        #pragma unroll
        for (int kk = 0; kk < BK; kk++) {
            float ra[8], rb[8];
            #pragma unroll
            for (int i = 0; i < 8; i++) ra[i] = As[kk][tr * 8 + i];
            #pragma unroll
            for (int j = 0; j < 8; j++) rb[j] = Bs[kk][tc * 8 + j];
            #pragma unroll
            for (int i = 0; i < 8; i++)
                #pragma unroll
                for (int j = 0; j < 8; j++) acc[i][j] += ra[i] * rb[j];
        }
        __syncthreads();
    }

    #pragma unroll
    for (int i = 0; i < 8; i++) {
        int gm = bm + tr * 8 + i;
        #pragma unroll
        for (int j = 0; j < 8; j++) {
            int gn = bn + tc * 8 + j;
            if (gn < N) C[(size_t)gm * N + gn] = acc[i][j] + bias[gn];
        }
    }
}

// ---------------------------------------------------------------------------
// Plain tiled SIMT GEMM: C = A @ W + bias (all fp32)
// ---------------------------------------------------------------------------
__global__ void gemm_kernel(const float* __restrict__ A, const float* __restrict__ W,
                            const float* __restrict__ bias, float* __restrict__ C,
                            int M, int N, int K) {
    const int BM = 128, BN = 128, BK = 16;
    __shared__ float As[BK][BM];
    __shared__ float Bs[BK][BN];

    const int tid = threadIdx.x;
    const int bm = blockIdx.y * BM;
    const int bn = blockIdx.x * BN;
    const int tr = tid >> 4;
    const int tc = tid & 15;

    float acc[8][8];
    #pragma unroll
    for (int i = 0; i < 8; i++)
        #pragma unroll
        for (int j = 0; j < 8; j++) acc[i][j] = 0.f;

    for (int k0 = 0; k0 < K; k0 += BK) {
        #pragma unroll
        for (int i = 0; i < 8; i++) {
            int idx = tid + i * 256;
            int m = idx >> 4, kk = idx & 15;
            As[kk][m] = A[(size_t)(bm + m) * K + k0 + kk];
        }
        #pragma unroll
        for (int i = 0; i < 8; i++) {
            int idx = tid + i * 256;
            int kk = idx >> 7, n = idx & 127;
            float v = 0.f;
            if (bn + n < N) v = W[(size_t)(k0 + kk) * N + bn + n];
            Bs[kk][n] = v;
        }
        __syncthreads();
        #pragma unroll
        for (int kk = 0; kk < BK; kk++) {
            float ra[8], rb[8];
            #pragma unroll
            for (int i = 0; i < 8; i++) ra[i] = As[kk][tr * 8 + i];
            #pragma unroll
            for (int j = 0; j < 8; j++) rb[j] = Bs[kk][tc * 8 + j];
            #pragma unroll
            for (int i = 0; i < 8; i++)
                #pragma unroll
                for (int j = 0; j < 8; j++) acc[i][j] += ra[i] * rb[j];
        }
        __syncthreads();
    }

    #pragma unroll
    for (int i = 0; i < 8; i++) {
        int gm = bm + tr * 8 + i;
        #pragma unroll
        for (int j = 0; j < 8; j++) {
            int gn = bn + tc * 8 + j;
            if (gn < N) C[(size_t)gm * N + gn] = acc[i][j] + bias[gn];
        }
    }
}

// ---------------------------------------------------------------------------
// MSDA core: one block per (b, nq). Softmax(4) + pixel coords in shared,
// then 768 outputs = sum over 4 points of bilinear-sampled value * weight.
// ---------------------------------------------------------------------------
__global__ void msda_kernel(const float* __restrict__ value,  // (B, NV, 768)
                            const float* __restrict__ offr,   // (B*NQ, 64)
                            const float* __restrict__ awr,    // (B*NQ, 32)
                            const float* __restrict__ refp,   // (B*NQ, 2)
                            float* __restrict__ out) {        // (B*NQ, 768)
    const int row = blockIdx.x;
    const int b = row / NQS;
    const int t = threadIdx.x;

    __shared__ float aw_s[32], x_s[32], y_s[32];
    if (t < 32) {
        const int h = t >> 2, p = t & 3;
        const size_t abase = (size_t)row * 32 + h * 4;
        float a0 = awr[abase + 0], a1 = awr[abase + 1];
        float a2 = awr[abase + 2], a3 = awr[abase + 3];
        float mx = fmaxf(fmaxf(a0, a1), fmaxf(a2, a3));
        float e0 = __expf(a0 - mx), e1 = __expf(a1 - mx);
        float e2 = __expf(a2 - mx), e3 = __expf(a3 - mx);
        float inv = 1.0f / (e0 + e1 + e2 + e3);
        float mine = (p == 0) ? e0 : (p == 1) ? e1 : (p == 2) ? e2 : e3;
        aw_s[t] = mine * inv;

        float rx = refp[(size_t)row * 2 + 0];
        float ry = refp[(size_t)row * 2 + 1];
        float ox = offr[(size_t)row * 64 + h * 8 + p * 2 + 0];
        float oy = offr[(size_t)row * 64 + h * 8 + p * 2 + 1];
        // loc = ref + off/[W,H];  pixel = loc*size - 0.5
        x_s[t] = rx * WFEAT + ox - 0.5f;
        y_s[t] = ry * HFEAT + oy - 0.5f;
    }
    __syncthreads();

    const size_t vbase = (size_t)b * NVS * E_DIM;
    #pragma unroll
    for (int i = 0; i < 3; i++) {
        int e = t + i * 256;
        int h = e / HDIM;
        float acc = 0.f;
        #pragma unroll
        for (int p = 0; p < 4; p++) {
            int s4 = h * 4 + p;
            float x = x_s[s4], y = y_s[s4];
            float x0 = floorf(x), y0 = floorf(y);
            float fx = x - x0, fy = y - y0;
            int ix0 = (int)x0, iy0 = (int)y0;
            int ix1 = ix0 + 1, iy1 = iy0 + 1;
            bool vx0 = (ix0 >= 0) && (ix0 < WFEAT);
            bool vx1 = (ix1 >= 0) && (ix1 < WFEAT);
            bool vy0 = (iy0 >= 0) && (iy0 < HFEAT);
            bool vy1 = (iy1 >= 0) && (iy1 < HFEAT);
            float sp = 0.f;
            if (vy0) {
                size_t rbase = vbase + (size_t)(iy0 * WFEAT) * E_DIM + e;
                if (vx0) sp += (1.f - fx) * (1.f - fy) * value[rbase + (size_t)ix0 * E_DIM];
                if (vx1) sp += fx * (1.f - fy) * value[rbase + (size_t)ix1 * E_DIM];
            }
            if (vy1) {
                size_t rbase = vbase + (size_t)(iy1 * WFEAT) * E_DIM + e;
                if (vx0) sp += (1.f - fx) * fy * value[rbase + (size_t)ix0 * E_DIM];
                if (vx1) sp += fx * fy * value[rbase + (size_t)ix1 * E_DIM];
            }
            acc += aw_s[s4] * sp;
        }
        out[(size_t)row * E_DIM + e] = acc;
    }
}

// ---------------------------------------------------------------------------
// Final: out = query + gamma * (LN_q(query) + proj_out)
// LN_q recomputed from stats (cheap, avoids storing q_ln)
// ---------------------------------------------------------------------------
__global__ void final_kernel(const float* __restrict__ query, const float* __restrict__ qstats,
                             const float* __restrict__ lnqw, const float* __restrict__ lnqb,
                             const float* __restrict__ go, const float* __restrict__ gamma,
                             float* __restrict__ out) {
    size_t base = ((size_t)blockIdx.x * 256 + threadIdx.x) * 4;
    #pragma unroll
    for (int j = 0; j < 4; j++) {
        size_t idx = base + j;
        int e = (int)(idx % E_DIM);
        int r = (int)(idx / E_DIM);
        float qv = query[idx];
        float qln = (qv - qstats[r * 2 + 0]) * qstats[r * 2 + 1] * lnqw[e] + lnqb[e];
        out[idx] = qv + gamma[e] * (qln + go[idx]);
    }
}

// ---------------------------------------------------------------------------
extern "C" void kernel_launch(void* const* d_in, const int* in_sizes, int n_in,
                              void* d_out, int out_size, void* d_ws, size_t ws_size,
                              hipStream_t stream) {
    (void)in_sizes; (void)n_in; (void)out_size; (void)ws_size;

    const float* query  = (const float*)d_in[0];
    const float* refp   = (const float*)d_in[1];
    const float* feat   = (const float*)d_in[2];
    // d_in[3] spatial_shapes (int32), d_in[4] level_start_index (int32): static
    const float* ln_q_w = (const float*)d_in[5];
    const float* ln_q_b = (const float*)d_in[6];
    const float* ln_f_w = (const float*)d_in[7];
    const float* ln_f_b = (const float*)d_in[8];
    const float* W_val  = (const float*)d_in[9];
    const float* b_val  = (const float*)d_in[10];
    const float* W_off  = (const float*)d_in[11];
    const float* b_off  = (const float*)d_in[12];
    const float* W_attn = (const float*)d_in[13];
    const float* b_attn = (const float*)d_in[14];
    const float* W_out  = (const float*)d_in[15];
    const float* b_out  = (const float*)d_in[16];
    const float* gamma  = (const float*)d_in[17];
    float* out = (float*)d_out;

    const int MQ = BB * NQS;   // 16384
    const int MV = BB * NVS;   // 36864

    // Workspace layout (bytes, fp32)
    char* ws = (char*)d_ws;
    float* q_stats = (float*)(ws + 0);            //  16384*2*4 =     131,072
    float* f_stats = (float*)(ws + 131072);       //  36864*2*4 =     294,912
    float* value   = (float*)(ws + 425984);       // 36864*768*4 = 113,246,208
    float* offr    = (float*)(ws + 113672192);    //  16384*64*4 =   4,194,304
    float* awr     = (float*)(ws + 117866496);    //  16384*32*4 =   2,097,152
    float* msda    = (float*)(ws + 119963648);    // 16384*768*4 =  50,331,648
    float* gout    = (float*)(ws + 170295296);    // 16384*768*4 =  50,331,648
    // total: 220,626,944 bytes

    // 1. LN stats
    row_stats_kernel<<<MQ, 256, 0, stream>>>(query, q_stats);
    row_stats_kernel<<<MV, 256, 0, stream>>>(feat, f_stats);

    // 2. value = LN(feat) @ W_value + b_value   (36864 x 768 x 768)
    gemm_ln_kernel<<<dim3(E_DIM / 128, MV / 128), 256, 0, stream>>>(
        feat, f_stats, ln_f_w, ln_f_b, W_val, b_val, value, MV, E_DIM, E_DIM);

    // 3. offsets / attn logits from LN(query)  (16384 x {64,32} x 768)
    gemm_ln_kernel<<<dim3(1, MQ / 128), 256, 0, stream>>>(
        query, q_stats, ln_q_w, ln_q_b, W_off, b_off, offr, MQ, NHEAD * NPTS * 2, E_DIM);
    gemm_ln_kernel<<<dim3(1, MQ / 128), 256, 0, stream>>>(
        query, q_stats, ln_q_w, ln_q_b, W_attn, b_attn, awr, MQ, NHEAD * NPTS, E_DIM);

    // 4. deformable sampling core
    msda_kernel<<<MQ, 256, 0, stream>>>(value, offr, awr, refp, msda);

    // 5. out projection (16384 x 768 x 768)
    gemm_kernel<<<dim3(E_DIM / 128, MQ / 128), 256, 0, stream>>>(
        msda, W_out, b_out, gout, MQ, E_DIM, E_DIM);

    // 6. final residual
    final_kernel<<<(MQ * E_DIM) / (256 * 4), 256, 0, stream>>>(
        query, q_stats, ln_q_w, ln_q_b, gout, gamma, out);
}

// Round 3
// 590.305 us; speedup vs baseline: 6.0226x; 6.0226x over previous
//
#include <hip/hip_runtime.h>

#define BB     4
#define NQS    4096
#define NVS    9216
#define E_DIM  768
#define NHEAD  8
#define NPTS   4
#define HDIM   96
#define HFEAT  96
#define WFEAT  96

typedef __attribute__((ext_vector_type(8))) short  s8v;    // 8 x bf16 (4 VGPRs)
typedef __attribute__((ext_vector_type(4))) float  f4v;    // MFMA acc

__device__ __forceinline__ unsigned short f2bf(float x) {
    unsigned int u = __builtin_bit_cast(unsigned int, x);
    unsigned int r = (u + 0x7fffu + ((u >> 16) & 1u)) >> 16;
    return (unsigned short)r;
}
__device__ __forceinline__ float bf2f(unsigned short s) {
    unsigned int u = ((unsigned int)s) << 16;
    return __builtin_bit_cast(float, u);
}

#define GLD16(gp, lp) \
    __builtin_amdgcn_global_load_lds( \
        (__attribute__((address_space(1))) void*)(gp), \
        (__attribute__((address_space(3))) void*)(lp), 16, 0, 0)

// ---------------------------------------------------------------------------
// Fused LayerNorm + bf16 cast (one pass). Optionally stores (mean, rstd).
// One block per row of 768, 256 threads.
// ---------------------------------------------------------------------------
template <bool STATS>
__global__ void ln_cast_kernel(const float* __restrict__ x, const float* __restrict__ w,
                               const float* __restrict__ b, unsigned short* __restrict__ out,
                               float* __restrict__ stats) {
    const int row = blockIdx.x;
    const int t = threadIdx.x;
    const float* xr = x + (size_t)row * E_DIM;

    float v0 = xr[t];
    float v1 = xr[t + 256];
    float v2 = xr[t + 512];
    float s1 = v0 + v1 + v2;
    float s2 = v0 * v0 + v1 * v1 + v2 * v2;

    __shared__ float sh[10];
    #pragma unroll
    for (int o = 32; o > 0; o >>= 1) {
        s1 += __shfl_down(s1, o, 64);
        s2 += __shfl_down(s2, o, 64);
    }
    const int lane = t & 63, wv = t >> 6;
    if (lane == 0) { sh[wv * 2] = s1; sh[wv * 2 + 1] = s2; }
    __syncthreads();
    if (t == 0) {
        float a = 0.f, c = 0.f;
        #pragma unroll
        for (int i = 0; i < 4; i++) { a += sh[i * 2]; c += sh[i * 2 + 1]; }
        float mean = a * (1.0f / E_DIM);
        float var = c * (1.0f / E_DIM) - mean * mean;
        sh[8] = mean;
        sh[9] = rsqrtf(var + 1e-6f);
        if (STATS) { stats[row * 2 + 0] = sh[8]; stats[row * 2 + 1] = sh[9]; }
    }
    __syncthreads();
    const float mean = sh[8], rstd = sh[9];
    const float vv[3] = {v0, v1, v2};
    #pragma unroll
    for (int i = 0; i < 3; i++) {
        int c = t + i * 256;
        out[(size_t)row * E_DIM + c] = f2bf((vv[i] - mean) * rstd * w[c] + b[c]);
    }
}

// ---------------------------------------------------------------------------
// 32x32 LDS tile transpose + bf16 cast: W[768][768] -> Wt[768][768] (Wt[n][k])
// ---------------------------------------------------------------------------
__global__ void transpose_cast_kernel(const float* __restrict__ W, unsigned short* __restrict__ Wt) {
    __shared__ float tile[32][33];
    const int bi = blockIdx.y * 32, bj = blockIdx.x * 32;
    const int t = threadIdx.x;
    const int r = t >> 5, c = t & 31;
    #pragma unroll
    for (int i = 0; i < 4; i++)
        tile[r + i * 8][c] = W[(size_t)(bi + r + i * 8) * E_DIM + bj + c];
    __syncthreads();
    #pragma unroll
    for (int i = 0; i < 4; i++)
        Wt[(size_t)(bj + r + i * 8) * E_DIM + bi + c] = f2bf(tile[c][r + i * 8]);
}

// ---------------------------------------------------------------------------
// Build concatenated + transposed + zero-padded query-proj weights:
// Wqc_t[128][768] bf16: rows 0-63 = W_off cols, 64-95 = W_attn cols, 96-127 = 0
// bcat[128] fp32 likewise.
// ---------------------------------------------------------------------------
__global__ void build_wqc_kernel(const float* __restrict__ W_off, const float* __restrict__ W_attn,
                                 const float* __restrict__ b_off, const float* __restrict__ b_attn,
                                 unsigned short* __restrict__ Wt, float* __restrict__ bcat) {
    const int idx = blockIdx.x * 256 + threadIdx.x;  // 128*768 total
    const int rrow = idx / E_DIM, k = idx % E_DIM;
    float v = 0.f;
    if (rrow < 64) v = W_off[(size_t)k * 64 + rrow];
    else if (rrow < 96) v = W_attn[(size_t)k * 32 + (rrow - 64)];
    Wt[idx] = f2bf(v);
    if (idx < 128) {
        float b = 0.f;
        if (idx < 64) b = b_off[idx];
        else if (idx < 96) b = b_attn[idx - 64];
        bcat[idx] = b;
    }
}

// ---------------------------------------------------------------------------
// bf16 MFMA NT-GEMM: C[M][ldC] = A[M][K](bf16) @ Bt[N][K](bf16)^T + bias[N]
// 128x128 tile, BK=32, 256 threads = 4 waves (2x2 of 64x64), 16x16x32 MFMA.
// Staging via global_load_lds(16B): LDS layout [rowhi][kseg][rlow] so frag
// ds_read_b128 is stride-16B across lanes (2-way bank alias = free).
// EPI: 0 = bf16 out + bias; 1 = fp32 out + bias; 2 = fused final residual.
// ---------------------------------------------------------------------------
template <int EPI>
__global__ __launch_bounds__(256, 2) void mfma_gemm(
    const unsigned short* __restrict__ A, const unsigned short* __restrict__ Bt,
    const float* __restrict__ bias, void* __restrict__ C, int K, int ldC,
    const float* __restrict__ query, const float* __restrict__ qstats,
    const float* __restrict__ lnw, const float* __restrict__ lnb,
    const float* __restrict__ gamma) {
    __shared__ unsigned short As[128 * 32];
    __shared__ unsigned short Bs[128 * 32];

    const int tid = threadIdx.x;
    const int wave = tid >> 6;
    const int lane = tid & 63;
    const int quad = lane >> 4;
    const int l16 = lane & 15;
    const int bm = blockIdx.y * 128;
    const int bn = blockIdx.x * 128;
    const int wrow = wave >> 1, wcol = wave & 1;

    f4v acc[4][4] = {};

    for (int k0 = 0; k0 < K; k0 += 32) {
        #pragma unroll
        for (int i = 0; i < 2; i++) {
            const int j = wave * 2 + i;           // 0..7
            const int rowhi = j >> 2, kseg = j & 3;
            const unsigned short* ga = A + (size_t)(bm + rowhi * 64 + lane) * K + k0 + kseg * 8;
            GLD16(ga, As + j * 512);
            const unsigned short* gb = Bt + (size_t)(bn + rowhi * 64 + lane) * K + k0 + kseg * 8;
            GLD16(gb, Bs + j * 512);
        }
        __syncthreads();

        s8v af[4], bfv[4];
        #pragma unroll
        for (int ti = 0; ti < 4; ti++) {
            af[ti]  = *(const s8v*)(As + ((size_t)(wrow * 4 + quad) * 64 + ti * 16 + l16) * 8);
            bfv[ti] = *(const s8v*)(Bs + ((size_t)(wcol * 4 + quad) * 64 + ti * 16 + l16) * 8);
        }
        #pragma unroll
        for (int ti = 0; ti < 4; ti++)
            #pragma unroll
            for (int tj = 0; tj < 4; tj++)
                acc[ti][tj] = __builtin_amdgcn_mfma_f32_16x16x32_bf16(af[ti], bfv[tj], acc[ti][tj], 0, 0, 0);
        __syncthreads();
    }

    #pragma unroll
    for (int ti = 0; ti < 4; ti++) {
        const int gm_base = bm + wrow * 64 + ti * 16 + quad * 4;
        #pragma unroll
        for (int tj = 0; tj < 4; tj++) {
            const int gn = bn + wcol * 64 + tj * 16 + l16;
            const float bv = bias[gn];
            #pragma unroll
            for (int r = 0; r < 4; r++) {
                const int gm = gm_base + r;
                const float v = acc[ti][tj][r] + bv;
                const size_t idx = (size_t)gm * ldC + gn;
                if (EPI == 0) {
                    ((unsigned short*)C)[idx] = f2bf(v);
                } else if (EPI == 1) {
                    ((float*)C)[idx] = v;
                } else {
                    const float qv = query[idx];
                    const float qln = (qv - qstats[gm * 2]) * qstats[gm * 2 + 1] * lnw[gn] + lnb[gn];
                    ((float*)C)[idx] = qv + gamma[gn] * (qln + v);
                }
            }
        }
    }
}

// ---------------------------------------------------------------------------
// MSDA core: one block per (b, nq), 384 threads (2 channels each, ushort2).
// Softmax(4) + pixel coords by threads 0-31; value is bf16.
// ---------------------------------------------------------------------------
__global__ void msda_kernel(const unsigned short* __restrict__ value,  // (B,NV,768) bf16
                            const float* __restrict__ oa,              // (B*NQ,128): 0-63 off, 64-95 attn
                            const float* __restrict__ refp,            // (B*NQ,2)
                            unsigned short* __restrict__ out) {        // (B*NQ,768) bf16
    const int row = blockIdx.x;
    const int b = row >> 12;   // / 4096
    const int t = threadIdx.x;

    __shared__ float aw_s[32], x_s[32], y_s[32];
    if (t < 32) {
        const int h = t >> 2, p = t & 3;
        const float* oar = oa + (size_t)row * 128;
        float a0 = oar[64 + h * 4 + 0], a1 = oar[64 + h * 4 + 1];
        float a2 = oar[64 + h * 4 + 2], a3 = oar[64 + h * 4 + 3];
        float mx = fmaxf(fmaxf(a0, a1), fmaxf(a2, a3));
        float e0 = __expf(a0 - mx), e1 = __expf(a1 - mx);
        float e2 = __expf(a2 - mx), e3 = __expf(a3 - mx);
        float inv = 1.0f / (e0 + e1 + e2 + e3);
        aw_s[t] = ((p == 0) ? e0 : (p == 1) ? e1 : (p == 2) ? e2 : e3) * inv;
        float rx = refp[(size_t)row * 2 + 0];
        float ry = refp[(size_t)row * 2 + 1];
        x_s[t] = rx * WFEAT + oar[h * 8 + p * 2 + 0] - 0.5f;
        y_s[t] = ry * HFEAT + oar[h * 8 + p * 2 + 1] - 0.5f;
    }
    __syncthreads();

    const int e0i = t * 2;          // channel pair
    const int h = e0i / HDIM;
    float acc0 = 0.f, acc1 = 0.f;
    const unsigned short* vb = value + (size_t)b * NVS * E_DIM + e0i;

    #pragma unroll
    for (int p = 0; p < 4; p++) {
        const int s4 = h * 4 + p;
        const float x = x_s[s4], y = y_s[s4];
        const float x0 = floorf(x), y0 = floorf(y);
        const float fx = x - x0, fy = y - y0;
        const int ix0 = (int)x0, iy0 = (int)y0;
        const int ix1 = ix0 + 1, iy1 = iy0 + 1;
        const bool vx0 = (ix0 >= 0) && (ix0 < WFEAT);
        const bool vx1 = (ix1 >= 0) && (ix1 < WFEAT);
        const bool vy0 = (iy0 >= 0) && (iy0 < HFEAT);
        const bool vy1 = (iy1 >= 0) && (iy1 < HFEAT);
        const float aw = aw_s[s4];
        float s0 = 0.f, s1 = 0.f;
        #pragma unroll
        for (int cy = 0; cy < 2; cy++) {
            const bool vy = cy ? vy1 : vy0;
            if (!vy) continue;
            const int iy = cy ? iy1 : iy0;
            const float wy = cy ? fy : (1.f - fy);
            #pragma unroll
            for (int cx = 0; cx < 2; cx++) {
                const bool vx = cx ? vx1 : vx0;
                if (!vx) continue;
                const int ix = cx ? ix1 : ix0;
                const float w = wy * (cx ? fx : (1.f - fx));
                const unsigned short* vp = vb + (size_t)(iy * WFEAT + ix) * E_DIM;
                ushort2 vv = *(const ushort2*)vp;
                s0 += w * bf2f(vv.x);
                s1 += w * bf2f(vv.y);
            }
        }
        acc0 += aw * s0;
        acc1 += aw * s1;
    }
    ushort2 o;
    o.x = f2bf(acc0);
    o.y = f2bf(acc1);
    *(ushort2*)(out + (size_t)row * E_DIM + e0i) = o;
}

// ---------------------------------------------------------------------------
extern "C" void kernel_launch(void* const* d_in, const int* in_sizes, int n_in,
                              void* d_out, int out_size, void* d_ws, size_t ws_size,
                              hipStream_t stream) {
    (void)in_sizes; (void)n_in; (void)out_size; (void)ws_size;

    const float* query  = (const float*)d_in[0];
    const float* refp   = (const float*)d_in[1];
    const float* feat   = (const float*)d_in[2];
    const float* ln_q_w = (const float*)d_in[5];
    const float* ln_q_b = (const float*)d_in[6];
    const float* ln_f_w = (const float*)d_in[7];
    const float* ln_f_b = (const float*)d_in[8];
    const float* W_val  = (const float*)d_in[9];
    const float* b_val  = (const float*)d_in[10];
    const float* W_off  = (const float*)d_in[11];
    const float* b_off  = (const float*)d_in[12];
    const float* W_attn = (const float*)d_in[13];
    const float* b_attn = (const float*)d_in[14];
    const float* W_out  = (const float*)d_in[15];
    const float* b_out  = (const float*)d_in[16];
    const float* gamma  = (const float*)d_in[17];
    float* out = (float*)d_out;

    const int MQ = BB * NQS;   // 16384
    const int MV = BB * NVS;   // 36864

    // Workspace layout (bytes)
    char* ws = (char*)d_ws;
    float*          q_stats = (float*)(ws + 0);                   //     131,072
    unsigned short* qbf     = (unsigned short*)(ws + 131072);     //  25,165,824
    unsigned short* fbf     = (unsigned short*)(ws + 25296896);   //  56,623,104
    unsigned short* val_bf  = (unsigned short*)(ws + 81920000);   //  56,623,104
    unsigned short* msda_bf = (unsigned short*)(ws + 138543104);  //  25,165,824
    float*          offattn = (float*)(ws + 163708928);           //   8,388,608
    unsigned short* Wv_t    = (unsigned short*)(ws + 172097536);  //   1,179,648
    unsigned short* Wo_t    = (unsigned short*)(ws + 173277184);  //   1,179,648
    unsigned short* Wqc_t   = (unsigned short*)(ws + 174456832);  //     196,608
    float*          bcat    = (float*)(ws + 174653440);           //         512
    // total ~174.7 MB

    // 1. LN + bf16 cast (query keeps stats for the fused final epilogue)
    ln_cast_kernel<true><<<MQ, 256, 0, stream>>>(query, ln_q_w, ln_q_b, qbf, q_stats);
    ln_cast_kernel<false><<<MV, 256, 0, stream>>>(feat, ln_f_w, ln_f_b, fbf, nullptr);

    // 2. weight prep (transpose + bf16)
    transpose_cast_kernel<<<dim3(24, 24), 256, 0, stream>>>(W_val, Wv_t);
    transpose_cast_kernel<<<dim3(24, 24), 256, 0, stream>>>(W_out, Wo_t);
    build_wqc_kernel<<<384, 256, 0, stream>>>(W_off, W_attn, b_off, b_attn, Wqc_t, bcat);

    // 3. value = LN(feat) @ W_value + b_value  (36864x768x768) -> bf16
    mfma_gemm<0><<<dim3(E_DIM / 128, MV / 128), 256, 0, stream>>>(
        fbf, Wv_t, b_val, val_bf, E_DIM, E_DIM, nullptr, nullptr, nullptr, nullptr, nullptr);

    // 4. offsets|attn = LN(q) @ [W_off|W_attn|0] (16384x128x768) -> fp32
    mfma_gemm<1><<<dim3(1, MQ / 128), 256, 0, stream>>>(
        qbf, Wqc_t, bcat, offattn, E_DIM, 128, nullptr, nullptr, nullptr, nullptr, nullptr);

    // 5. deformable sampling -> bf16
    msda_kernel<<<MQ, 384, 0, stream>>>(val_bf, offattn, refp, msda_bf);

    // 6. out-proj + fused final residual: out = q + gamma*(LNq + msda@W_out + b_out)
    mfma_gemm<2><<<dim3(E_DIM / 128, MQ / 128), 256, 0, stream>>>(
        msda_bf, Wo_t, b_out, out, E_DIM, E_DIM, query, q_stats, ln_q_w, ln_q_b, gamma);
}

// Round 4
// 538.642 us; speedup vs baseline: 6.6003x; 1.0959x over previous
//
#include <hip/hip_runtime.h>

#define BB     4
#define NQS    4096
#define NVS    9216
#define E_DIM  768
#define NHEAD  8
#define NPTS   4
#define HDIM   96
#define HFEAT  96
#define WFEAT  96

typedef __attribute__((ext_vector_type(8))) short  s8v;    // 8 x bf16 (4 VGPRs)
typedef __attribute__((ext_vector_type(4))) float  f4v;    // MFMA acc

__device__ __forceinline__ unsigned short f2bf(float x) {
    unsigned int u = __builtin_bit_cast(unsigned int, x);
    unsigned int r = (u + 0x7fffu + ((u >> 16) & 1u)) >> 16;
    return (unsigned short)r;
}
__device__ __forceinline__ float bf2f(unsigned short s) {
    unsigned int u = ((unsigned int)s) << 16;
    return __builtin_bit_cast(float, u);
}
__device__ __forceinline__ float bf2f_s(short s) {
    return bf2f((unsigned short)s);
}

#define GLD16(gp, lp) \
    __builtin_amdgcn_global_load_lds( \
        (__attribute__((address_space(1))) void*)(gp), \
        (__attribute__((address_space(3))) void*)(lp), 16, 0, 0)

// ---------------------------------------------------------------------------
// Fused LayerNorm + bf16 cast (one pass). Optionally stores (mean, rstd).
// ---------------------------------------------------------------------------
template <bool STATS>
__global__ void ln_cast_kernel(const float* __restrict__ x, const float* __restrict__ w,
                               const float* __restrict__ b, unsigned short* __restrict__ out,
                               float* __restrict__ stats) {
    const int row = blockIdx.x;
    const int t = threadIdx.x;
    const float* xr = x + (size_t)row * E_DIM;

    float v0 = xr[t];
    float v1 = xr[t + 256];
    float v2 = xr[t + 512];
    float s1 = v0 + v1 + v2;
    float s2 = v0 * v0 + v1 * v1 + v2 * v2;

    __shared__ float sh[10];
    #pragma unroll
    for (int o = 32; o > 0; o >>= 1) {
        s1 += __shfl_down(s1, o, 64);
        s2 += __shfl_down(s2, o, 64);
    }
    const int lane = t & 63, wv = t >> 6;
    if (lane == 0) { sh[wv * 2] = s1; sh[wv * 2 + 1] = s2; }
    __syncthreads();
    if (t == 0) {
        float a = 0.f, c = 0.f;
        #pragma unroll
        for (int i = 0; i < 4; i++) { a += sh[i * 2]; c += sh[i * 2 + 1]; }
        float mean = a * (1.0f / E_DIM);
        float var = c * (1.0f / E_DIM) - mean * mean;
        sh[8] = mean;
        sh[9] = rsqrtf(var + 1e-6f);
        if (STATS) { stats[row * 2 + 0] = sh[8]; stats[row * 2 + 1] = sh[9]; }
    }
    __syncthreads();
    const float mean = sh[8], rstd = sh[9];
    const float vv[3] = {v0, v1, v2};
    #pragma unroll
    for (int i = 0; i < 3; i++) {
        int c = t + i * 256;
        out[(size_t)row * E_DIM + c] = f2bf((vv[i] - mean) * rstd * w[c] + b[c]);
    }
}

// ---------------------------------------------------------------------------
// 32x32 LDS tile transpose + bf16 cast: W[768][768] -> Wt[768][768] (Wt[n][k])
// ---------------------------------------------------------------------------
__global__ void transpose_cast_kernel(const float* __restrict__ W, unsigned short* __restrict__ Wt) {
    __shared__ float tile[32][33];
    const int bi = blockIdx.y * 32, bj = blockIdx.x * 32;
    const int t = threadIdx.x;
    const int r = t >> 5, c = t & 31;
    #pragma unroll
    for (int i = 0; i < 4; i++)
        tile[r + i * 8][c] = W[(size_t)(bi + r + i * 8) * E_DIM + bj + c];
    __syncthreads();
    #pragma unroll
    for (int i = 0; i < 4; i++)
        Wt[(size_t)(bj + r + i * 8) * E_DIM + bi + c] = f2bf(tile[c][r + i * 8]);
}

// ---------------------------------------------------------------------------
// Concatenated + transposed + zero-padded query-proj weights (off|attn|pad)
// ---------------------------------------------------------------------------
__global__ void build_wqc_kernel(const float* __restrict__ W_off, const float* __restrict__ W_attn,
                                 const float* __restrict__ b_off, const float* __restrict__ b_attn,
                                 unsigned short* __restrict__ Wt, float* __restrict__ bcat) {
    const int idx = blockIdx.x * 256 + threadIdx.x;  // 128*768 total
    const int rrow = idx / E_DIM, k = idx % E_DIM;
    float v = 0.f;
    if (rrow < 64) v = W_off[(size_t)k * 64 + rrow];
    else if (rrow < 96) v = W_attn[(size_t)k * 32 + (rrow - 64)];
    Wt[idx] = f2bf(v);
    if (idx < 128) {
        float b = 0.f;
        if (idx < 64) b = b_off[idx];
        else if (idx < 96) b = b_attn[idx - 64];
        bcat[idx] = b;
    }
}

// ---------------------------------------------------------------------------
// bf16 MFMA NT-GEMM: C = A[M,K](bf16) @ Bt[N,K](bf16)^T + bias[N]
// 128x128 tile, BK=32, 4 waves (2x2 of 64x64), 16x16x32 MFMA, GLD16 staging.
// EPI: 0 = bf16 out in (B,H,S,D) layout (value GEMM)
//      1 = fp32 out + bias       (off/attn GEMM)
//      2 = fp32 fused final residual (out-proj GEMM)
// ---------------------------------------------------------------------------
template <int EPI>
__global__ __launch_bounds__(256, 2) void mfma_gemm(
    const unsigned short* __restrict__ A, const unsigned short* __restrict__ Bt,
    const float* __restrict__ bias, void* __restrict__ C, int K, int ldC,
    const float* __restrict__ query, const float* __restrict__ qstats,
    const float* __restrict__ lnw, const float* __restrict__ lnb,
    const float* __restrict__ gamma) {
    __shared__ unsigned short As[128 * 32];
    __shared__ unsigned short Bs[128 * 32];

    const int tid = threadIdx.x;
    const int wave = tid >> 6;
    const int lane = tid & 63;
    const int quad = lane >> 4;
    const int l16 = lane & 15;
    const int bm = blockIdx.y * 128;
    const int bn = blockIdx.x * 128;
    const int wrow = wave >> 1, wcol = wave & 1;

    f4v acc[4][4] = {};

    for (int k0 = 0; k0 < K; k0 += 32) {
        #pragma unroll
        for (int i = 0; i < 2; i++) {
            const int j = wave * 2 + i;           // 0..7
            const int rowhi = j >> 2, kseg = j & 3;
            const unsigned short* ga = A + (size_t)(bm + rowhi * 64 + lane) * K + k0 + kseg * 8;
            GLD16(ga, As + j * 512);
            const unsigned short* gb = Bt + (size_t)(bn + rowhi * 64 + lane) * K + k0 + kseg * 8;
            GLD16(gb, Bs + j * 512);
        }
        __syncthreads();

        s8v af[4], bfv[4];
        #pragma unroll
        for (int ti = 0; ti < 4; ti++) {
            af[ti]  = *(const s8v*)(As + ((size_t)(wrow * 4 + quad) * 64 + ti * 16 + l16) * 8);
            bfv[ti] = *(const s8v*)(Bs + ((size_t)(wcol * 4 + quad) * 64 + ti * 16 + l16) * 8);
        }
        #pragma unroll
        for (int ti = 0; ti < 4; ti++)
            #pragma unroll
            for (int tj = 0; tj < 4; tj++)
                acc[ti][tj] = __builtin_amdgcn_mfma_f32_16x16x32_bf16(af[ti], bfv[tj], acc[ti][tj], 0, 0, 0);
        __syncthreads();
    }

    #pragma unroll
    for (int ti = 0; ti < 4; ti++) {
        const int gm_base = bm + wrow * 64 + ti * 16 + quad * 4;
        #pragma unroll
        for (int tj = 0; tj < 4; tj++) {
            const int gn = bn + wcol * 64 + tj * 16 + l16;
            const float bv = bias[gn];
            #pragma unroll
            for (int r = 0; r < 4; r++) {
                const int gm = gm_base + r;
                const float v = acc[ti][tj][r] + bv;
                if (EPI == 0) {
                    // value in (B, H, S, D): b=gm/NVS, s=gm%NVS, h=gn/HDIM, d=gn%HDIM
                    const int b = gm / NVS, s = gm - b * NVS;
                    const int hh = gn / HDIM, dd = gn - hh * HDIM;
                    const size_t vidx = (((size_t)b * NHEAD + hh) * NVS + s) * HDIM + dd;
                    ((unsigned short*)C)[vidx] = f2bf(v);
                } else if (EPI == 1) {
                    ((float*)C)[(size_t)gm * ldC + gn] = v;
                } else {
                    const size_t idx = (size_t)gm * ldC + gn;
                    const float qv = query[idx];
                    const float qln = (qv - qstats[gm * 2]) * qstats[gm * 2 + 1] * lnw[gn] + lnb[gn];
                    ((float*)C)[idx] = qv + gamma[gn] * (qln + v);
                }
            }
        }
    }
}

// ---------------------------------------------------------------------------
// MSDA core v2: grid (8 heads, 512); block 384 = 32 rows x 12 lanes.
// Each thread: 8 channels (ushort8 = 16 B loads) of one (row, head).
// value layout (B, H, S, D) -> per-head slice 1.77 MB (XCD-L2 resident).
// Branchless corners: clamped index, zeroed weight.
// ---------------------------------------------------------------------------
__global__ __launch_bounds__(384) void msda_kernel(
    const unsigned short* __restrict__ value,  // (B, 8, 9216, 96) bf16
    const float* __restrict__ oa,              // (B*NQ, 128): 0-63 off, 64-95 attn
    const float* __restrict__ refp,            // (B*NQ, 2)
    unsigned short* __restrict__ out) {        // (B*NQ, 768) bf16
    const int h = blockIdx.x;          // head
    const int row0 = blockIdx.y * 32;
    const int t = threadIdx.x;

    __shared__ float x_s[128], y_s[128], aw_s[128];
    if (t < 32) {
        const int row = row0 + t;
        const float* oar = oa + (size_t)row * 128;
        float a0 = oar[64 + h * 4 + 0], a1 = oar[64 + h * 4 + 1];
        float a2 = oar[64 + h * 4 + 2], a3 = oar[64 + h * 4 + 3];
        float mx = fmaxf(fmaxf(a0, a1), fmaxf(a2, a3));
        float e0 = __expf(a0 - mx), e1 = __expf(a1 - mx);
        float e2 = __expf(a2 - mx), e3 = __expf(a3 - mx);
        float inv = 1.0f / (e0 + e1 + e2 + e3);
        float rx = refp[(size_t)row * 2 + 0] * WFEAT - 0.5f;
        float ry = refp[(size_t)row * 2 + 1] * HFEAT - 0.5f;
        aw_s[t * 4 + 0] = e0 * inv;
        aw_s[t * 4 + 1] = e1 * inv;
        aw_s[t * 4 + 2] = e2 * inv;
        aw_s[t * 4 + 3] = e3 * inv;
        #pragma unroll
        for (int p = 0; p < 4; p++) {
            x_s[t * 4 + p] = rx + oar[h * 8 + p * 2 + 0];
            y_s[t * 4 + p] = ry + oar[h * 8 + p * 2 + 1];
        }
    }
    __syncthreads();

    const int r = t / 12;              // 0..31
    const int j = t - r * 12;          // 0..11
    const int row = row0 + r;
    const int b = row >> 12;           // / NQS
    const unsigned short* vb = value + ((size_t)(b * NHEAD + h) * NVS) * HDIM + j * 8;

    float acc[8] = {};
    #pragma unroll
    for (int p = 0; p < 4; p++) {
        const float x = x_s[r * 4 + p];
        const float y = y_s[r * 4 + p];
        const float aw = aw_s[r * 4 + p];
        const float x0f = floorf(x), y0f = floorf(y);
        const float fx = x - x0f, fy = y - y0f;
        const int ix0 = (int)x0f, iy0 = (int)y0f;
        const int ix1 = ix0 + 1, iy1 = iy0 + 1;
        const float wx0 = (ix0 >= 0 && ix0 < WFEAT) ? (1.f - fx) : 0.f;
        const float wx1 = (ix1 >= 0 && ix1 < WFEAT) ? fx : 0.f;
        const float wy0 = (iy0 >= 0 && iy0 < HFEAT) ? (1.f - fy) : 0.f;
        const float wy1 = (iy1 >= 0 && iy1 < HFEAT) ? fy : 0.f;
        const int cx0 = min(max(ix0, 0), WFEAT - 1);
        const int cx1 = min(max(ix1, 0), WFEAT - 1);
        const int cy0 = min(max(iy0, 0), HFEAT - 1);
        const int cy1 = min(max(iy1, 0), HFEAT - 1);
        const float w00 = aw * wy0 * wx0, w01 = aw * wy0 * wx1;
        const float w10 = aw * wy1 * wx0, w11 = aw * wy1 * wx1;
        const s8v v00 = *(const s8v*)(vb + (size_t)(cy0 * WFEAT + cx0) * HDIM);
        const s8v v01 = *(const s8v*)(vb + (size_t)(cy0 * WFEAT + cx1) * HDIM);
        const s8v v10 = *(const s8v*)(vb + (size_t)(cy1 * WFEAT + cx0) * HDIM);
        const s8v v11 = *(const s8v*)(vb + (size_t)(cy1 * WFEAT + cx1) * HDIM);
        #pragma unroll
        for (int k = 0; k < 8; k++) {
            acc[k] += w00 * bf2f_s(v00[k]) + w01 * bf2f_s(v01[k])
                    + w10 * bf2f_s(v10[k]) + w11 * bf2f_s(v11[k]);
        }
    }

    s8v o;
    #pragma unroll
    for (int k = 0; k < 8; k++) o[k] = (short)f2bf(acc[k]);
    *(s8v*)(out + (size_t)row * E_DIM + h * HDIM + j * 8) = o;
}

// ---------------------------------------------------------------------------
extern "C" void kernel_launch(void* const* d_in, const int* in_sizes, int n_in,
                              void* d_out, int out_size, void* d_ws, size_t ws_size,
                              hipStream_t stream) {
    (void)in_sizes; (void)n_in; (void)out_size; (void)ws_size;

    const float* query  = (const float*)d_in[0];
    const float* refp   = (const float*)d_in[1];
    const float* feat   = (const float*)d_in[2];
    const float* ln_q_w = (const float*)d_in[5];
    const float* ln_q_b = (const float*)d_in[6];
    const float* ln_f_w = (const float*)d_in[7];
    const float* ln_f_b = (const float*)d_in[8];
    const float* W_val  = (const float*)d_in[9];
    const float* b_val  = (const float*)d_in[10];
    const float* W_off  = (const float*)d_in[11];
    const float* b_off  = (const float*)d_in[12];
    const float* W_attn = (const float*)d_in[13];
    const float* b_attn = (const float*)d_in[14];
    const float* W_out  = (const float*)d_in[15];
    const float* b_out  = (const float*)d_in[16];
    const float* gamma  = (const float*)d_in[17];
    float* out = (float*)d_out;

    const int MQ = BB * NQS;   // 16384
    const int MV = BB * NVS;   // 36864

    // Workspace layout (bytes)
    char* ws = (char*)d_ws;
    float*          q_stats = (float*)(ws + 0);                   //     131,072
    unsigned short* qbf     = (unsigned short*)(ws + 131072);     //  25,165,824
    unsigned short* fbf     = (unsigned short*)(ws + 25296896);   //  56,623,104
    unsigned short* val_bf  = (unsigned short*)(ws + 81920000);   //  56,623,104 (B,H,S,D)
    unsigned short* msda_bf = (unsigned short*)(ws + 138543104);  //  25,165,824
    float*          offattn = (float*)(ws + 163708928);           //   8,388,608
    unsigned short* Wv_t    = (unsigned short*)(ws + 172097536);  //   1,179,648
    unsigned short* Wo_t    = (unsigned short*)(ws + 173277184);  //   1,179,648
    unsigned short* Wqc_t   = (unsigned short*)(ws + 174456832);  //     196,608
    float*          bcat    = (float*)(ws + 174653440);           //         512

    // 1. LN + bf16 cast
    ln_cast_kernel<true><<<MQ, 256, 0, stream>>>(query, ln_q_w, ln_q_b, qbf, q_stats);
    ln_cast_kernel<false><<<MV, 256, 0, stream>>>(feat, ln_f_w, ln_f_b, fbf, nullptr);

    // 2. weight prep
    transpose_cast_kernel<<<dim3(24, 24), 256, 0, stream>>>(W_val, Wv_t);
    transpose_cast_kernel<<<dim3(24, 24), 256, 0, stream>>>(W_out, Wo_t);
    build_wqc_kernel<<<384, 256, 0, stream>>>(W_off, W_attn, b_off, b_attn, Wqc_t, bcat);

    // 3. value = LN(feat) @ W_value + b_value -> bf16, (B,H,S,D) layout
    mfma_gemm<0><<<dim3(E_DIM / 128, MV / 128), 256, 0, stream>>>(
        fbf, Wv_t, b_val, val_bf, E_DIM, E_DIM, nullptr, nullptr, nullptr, nullptr, nullptr);

    // 4. offsets|attn = LN(q) @ [W_off|W_attn|0] -> fp32 (16384x128)
    mfma_gemm<1><<<dim3(1, MQ / 128), 256, 0, stream>>>(
        qbf, Wqc_t, bcat, offattn, E_DIM, 128, nullptr, nullptr, nullptr, nullptr, nullptr);

    // 5. deformable sampling -> bf16 (row-major B*NQ x 768)
    msda_kernel<<<dim3(NHEAD, MQ / 32), 384, 0, stream>>>(val_bf, offattn, refp, msda_bf);

    // 6. out-proj + fused final residual
    mfma_gemm<2><<<dim3(E_DIM / 128, MQ / 128), 256, 0, stream>>>(
        msda_bf, Wo_t, b_out, out, E_DIM, E_DIM, query, q_stats, ln_q_w, ln_q_b, gamma);
}

// Round 5
// 524.860 us; speedup vs baseline: 6.7736x; 1.0263x over previous
//
#include <hip/hip_runtime.h>

#define BB     4
#define NQS    4096
#define NVS    9216
#define E_DIM  768
#define NHEAD  8
#define NPTS   4
#define HDIM   96
#define HFEAT  96
#define WFEAT  96

typedef __attribute__((ext_vector_type(8))) short  s8v;    // 8 x bf16 (4 VGPRs)
typedef __attribute__((ext_vector_type(4))) short  s4v;    // 4 x bf16
typedef __attribute__((ext_vector_type(4))) float  f4v;    // MFMA acc

__device__ __forceinline__ unsigned short f2bf(float x) {
    unsigned int u = __builtin_bit_cast(unsigned int, x);
    unsigned int r = (u + 0x7fffu + ((u >> 16) & 1u)) >> 16;
    return (unsigned short)r;
}
__device__ __forceinline__ float bf2f(unsigned short s) {
    unsigned int u = ((unsigned int)s) << 16;
    return __builtin_bit_cast(float, u);
}
__device__ __forceinline__ float bf2f_s(short s) {
    return bf2f((unsigned short)s);
}

#define GLD16(gp, lp) \
    __builtin_amdgcn_global_load_lds( \
        (__attribute__((address_space(1))) void*)(gp), \
        (__attribute__((address_space(3))) void*)(lp), 16, 0, 0)

// ---------------------------------------------------------------------------
// Fused LayerNorm + bf16 cast, vectorized: 192 threads, float4 in / ushort4 out.
// ---------------------------------------------------------------------------
template <bool STATS>
__global__ __launch_bounds__(192) void ln_cast_kernel(
    const float* __restrict__ x, const float* __restrict__ w,
    const float* __restrict__ b, unsigned short* __restrict__ out,
    float* __restrict__ stats) {
    const int row = blockIdx.x;
    const int t = threadIdx.x;   // 0..191
    const float4 v = ((const float4*)(x + (size_t)row * E_DIM))[t];
    float s1 = v.x + v.y + v.z + v.w;
    float s2 = v.x * v.x + v.y * v.y + v.z * v.z + v.w * v.w;

    __shared__ float sh[8];
    #pragma unroll
    for (int o = 32; o > 0; o >>= 1) {
        s1 += __shfl_down(s1, o, 64);
        s2 += __shfl_down(s2, o, 64);
    }
    const int lane = t & 63, wv = t >> 6;
    if (lane == 0) { sh[wv * 2] = s1; sh[wv * 2 + 1] = s2; }
    __syncthreads();
    if (t == 0) {
        float a = sh[0] + sh[2] + sh[4];
        float c = sh[1] + sh[3] + sh[5];
        float mean = a * (1.0f / E_DIM);
        float var = c * (1.0f / E_DIM) - mean * mean;
        sh[6] = mean;
        sh[7] = rsqrtf(var + 1e-6f);
        if (STATS) { stats[row * 2 + 0] = sh[6]; stats[row * 2 + 1] = sh[7]; }
    }
    __syncthreads();
    const float mean = sh[6], rstd = sh[7];
    const float4 w4 = ((const float4*)w)[t];
    const float4 b4 = ((const float4*)b)[t];
    s4v o;
    o[0] = (short)f2bf((v.x - mean) * rstd * w4.x + b4.x);
    o[1] = (short)f2bf((v.y - mean) * rstd * w4.y + b4.y);
    o[2] = (short)f2bf((v.z - mean) * rstd * w4.z + b4.z);
    o[3] = (short)f2bf((v.w - mean) * rstd * w4.w + b4.w);
    ((s4v*)(out + (size_t)row * E_DIM))[t] = o;
}

// ---------------------------------------------------------------------------
// 32x32 LDS tile transpose + bf16 cast: W[768][768] -> Wt[768][768] (Wt[n][k])
// ---------------------------------------------------------------------------
__global__ void transpose_cast_kernel(const float* __restrict__ W, unsigned short* __restrict__ Wt) {
    __shared__ float tile[32][33];
    const int bi = blockIdx.y * 32, bj = blockIdx.x * 32;
    const int t = threadIdx.x;
    const int r = t >> 5, c = t & 31;
    #pragma unroll
    for (int i = 0; i < 4; i++)
        tile[r + i * 8][c] = W[(size_t)(bi + r + i * 8) * E_DIM + bj + c];
    __syncthreads();
    #pragma unroll
    for (int i = 0; i < 4; i++)
        Wt[(size_t)(bj + r + i * 8) * E_DIM + bi + c] = f2bf(tile[c][r + i * 8]);
}

// ---------------------------------------------------------------------------
// Concatenated + transposed + zero-padded query-proj weights (off|attn|pad)
// ---------------------------------------------------------------------------
__global__ void build_wqc_kernel(const float* __restrict__ W_off, const float* __restrict__ W_attn,
                                 const float* __restrict__ b_off, const float* __restrict__ b_attn,
                                 unsigned short* __restrict__ Wt, float* __restrict__ bcat) {
    const int idx = blockIdx.x * 256 + threadIdx.x;  // 128*768 total
    const int rrow = idx / E_DIM, k = idx % E_DIM;
    float v = 0.f;
    if (rrow < 64) v = W_off[(size_t)k * 64 + rrow];
    else if (rrow < 96) v = W_attn[(size_t)k * 32 + (rrow - 64)];
    Wt[idx] = f2bf(v);
    if (idx < 128) {
        float b = 0.f;
        if (idx < 64) b = b_off[idx];
        else if (idx < 96) b = b_attn[idx - 64];
        bcat[idx] = b;
    }
}

// ---------------------------------------------------------------------------
// bf16 MFMA NT-GEMM v2: C = A[M,K](bf16) @ Bt[N,K](bf16)^T + bias[N], K=768.
// 128x128 tile, BK=64, 4 waves (2x2 of 64x64), 16x16x32 MFMA.
// A staged via global_load_lds(16B) into 16 KB LDS; B fragments loaded
// DIRECTLY from global (weights are 1.2 MB -> L2-resident across all row
// blocks), issued before the mid-barrier so they overlap the A DMA.
// 12 K-iterations, 32 MFMA per wave per barrier pair.
// EPI: 0 = bf16 out in (B,H,S,D) layout; 1 = fp32 out + bias;
//      2 = fp32 fused final residual.
// ---------------------------------------------------------------------------
template <int EPI>
__global__ __launch_bounds__(256, 2) void mfma_gemm(
    const unsigned short* __restrict__ A, const unsigned short* __restrict__ Bt,
    const float* __restrict__ bias, void* __restrict__ C, int ldC,
    const float* __restrict__ query, const float* __restrict__ qstats,
    const float* __restrict__ lnw, const float* __restrict__ lnb,
    const float* __restrict__ gamma) {
    __shared__ unsigned short As[128 * 64];   // [kseg 0..7][row 0..127][8]

    constexpr int K = E_DIM;
    const int tid = threadIdx.x;
    const int wave = tid >> 6;
    const int lane = tid & 63;
    const int quad = lane >> 4;
    const int l16 = lane & 15;
    const int bm = blockIdx.y * 128;
    const int bn = blockIdx.x * 128;
    const int wrow = wave >> 1, wcol = wave & 1;

    // B column base pointers (include quad*8 k-offset)
    const unsigned short* bcol[4];
    #pragma unroll
    for (int tj = 0; tj < 4; tj++)
        bcol[tj] = Bt + (size_t)(bn + wcol * 64 + tj * 16 + l16) * K + quad * 8;

    // A staging: chunk = wave*4+i in 0..15; s=chunk>>1, r=(chunk&1)*64+lane
    const unsigned short* arow[4];
    unsigned short* aldst[4];
    #pragma unroll
    for (int i = 0; i < 4; i++) {
        const int chunk = wave * 4 + i;
        const int s = chunk >> 1, r = (chunk & 1) * 64 + lane;
        arow[i] = A + (size_t)(bm + r) * K + s * 8;
        aldst[i] = As + chunk * 512;          // 64 lanes * 16 B per chunk
    }

    f4v acc[4][4] = {};

    for (int k0 = 0; k0 < K; k0 += 64) {
        #pragma unroll
        for (int i = 0; i < 4; i++)
            GLD16(arow[i] + k0, aldst[i]);

        // B fragments direct from global (L2-hot), in flight with the A DMA
        s8v bcur[4][2];
        #pragma unroll
        for (int tj = 0; tj < 4; tj++) {
            bcur[tj][0] = *(const s8v*)(bcol[tj] + k0);
            bcur[tj][1] = *(const s8v*)(bcol[tj] + k0 + 32);
        }

        __syncthreads();

        #pragma unroll
        for (int c = 0; c < 2; c++) {
            s8v af[4];
            #pragma unroll
            for (int ti = 0; ti < 4; ti++)
                af[ti] = *(const s8v*)(As + ((size_t)((c * 4 + quad) * 128 + wrow * 64 + ti * 16 + l16)) * 8);
            #pragma unroll
            for (int ti = 0; ti < 4; ti++)
                #pragma unroll
                for (int tj = 0; tj < 4; tj++)
                    acc[ti][tj] = __builtin_amdgcn_mfma_f32_16x16x32_bf16(af[ti], bcur[tj][c], acc[ti][tj], 0, 0, 0);
        }
        __syncthreads();
    }

    #pragma unroll
    for (int ti = 0; ti < 4; ti++) {
        const int gm_base = bm + wrow * 64 + ti * 16 + quad * 4;
        #pragma unroll
        for (int tj = 0; tj < 4; tj++) {
            const int gn = bn + wcol * 64 + tj * 16 + l16;
            const float bv = bias[gn];
            #pragma unroll
            for (int r = 0; r < 4; r++) {
                const int gm = gm_base + r;
                const float v = acc[ti][tj][r] + bv;
                if (EPI == 0) {
                    const int b = gm / NVS, s = gm - b * NVS;
                    const int hh = gn / HDIM, dd = gn - hh * HDIM;
                    const size_t vidx = (((size_t)b * NHEAD + hh) * NVS + s) * HDIM + dd;
                    ((unsigned short*)C)[vidx] = f2bf(v);
                } else if (EPI == 1) {
                    ((float*)C)[(size_t)gm * ldC + gn] = v;
                } else {
                    const size_t idx = (size_t)gm * ldC + gn;
                    const float qv = query[idx];
                    const float qln = (qv - qstats[gm * 2]) * qstats[gm * 2 + 1] * lnw[gn] + lnb[gn];
                    ((float*)C)[idx] = qv + gamma[gn] * (qln + v);
                }
            }
        }
    }
}

// ---------------------------------------------------------------------------
// MSDA core: grid (8 heads, 512); block 384 = 32 rows x 12 lanes.
// Each thread: 8 channels (16 B loads) of one (row, head).
// value layout (B, H, S, D) -> per-head slice 1.77 MB (XCD-L2 resident;
// gridDim.x=8 pins head h to XCD h under round-robin block dispatch).
// ---------------------------------------------------------------------------
__global__ __launch_bounds__(384) void msda_kernel(
    const unsigned short* __restrict__ value,  // (B, 8, 9216, 96) bf16
    const float* __restrict__ oa,              // (B*NQ, 128): 0-63 off, 64-95 attn
    const float* __restrict__ refp,            // (B*NQ, 2)
    unsigned short* __restrict__ out) {        // (B*NQ, 768) bf16
    const int h = blockIdx.x;
    const int row0 = blockIdx.y * 32;
    const int t = threadIdx.x;

    __shared__ float x_s[128], y_s[128], aw_s[128];
    if (t < 32) {
        const int row = row0 + t;
        const float* oar = oa + (size_t)row * 128;
        float a0 = oar[64 + h * 4 + 0], a1 = oar[64 + h * 4 + 1];
        float a2 = oar[64 + h * 4 + 2], a3 = oar[64 + h * 4 + 3];
        float mx = fmaxf(fmaxf(a0, a1), fmaxf(a2, a3));
        float e0 = __expf(a0 - mx), e1 = __expf(a1 - mx);
        float e2 = __expf(a2 - mx), e3 = __expf(a3 - mx);
        float inv = 1.0f / (e0 + e1 + e2 + e3);
        float rx = refp[(size_t)row * 2 + 0] * WFEAT - 0.5f;
        float ry = refp[(size_t)row * 2 + 1] * HFEAT - 0.5f;
        aw_s[t * 4 + 0] = e0 * inv;
        aw_s[t * 4 + 1] = e1 * inv;
        aw_s[t * 4 + 2] = e2 * inv;
        aw_s[t * 4 + 3] = e3 * inv;
        #pragma unroll
        for (int p = 0; p < 4; p++) {
            x_s[t * 4 + p] = rx + oar[h * 8 + p * 2 + 0];
            y_s[t * 4 + p] = ry + oar[h * 8 + p * 2 + 1];
        }
    }
    __syncthreads();

    const int r = t / 12;              // 0..31
    const int j = t - r * 12;          // 0..11
    const int row = row0 + r;
    const int b = row >> 12;           // / NQS
    const unsigned short* vb = value + ((size_t)(b * NHEAD + h) * NVS) * HDIM + j * 8;

    float acc[8] = {};
    #pragma unroll
    for (int p = 0; p < 4; p++) {
        const float x = x_s[r * 4 + p];
        const float y = y_s[r * 4 + p];
        const float aw = aw_s[r * 4 + p];
        const float x0f = floorf(x), y0f = floorf(y);
        const float fx = x - x0f, fy = y - y0f;
        const int ix0 = (int)x0f, iy0 = (int)y0f;
        const int ix1 = ix0 + 1, iy1 = iy0 + 1;
        const float wx0 = (ix0 >= 0 && ix0 < WFEAT) ? (1.f - fx) : 0.f;
        const float wx1 = (ix1 >= 0 && ix1 < WFEAT) ? fx : 0.f;
        const float wy0 = (iy0 >= 0 && iy0 < HFEAT) ? (1.f - fy) : 0.f;
        const float wy1 = (iy1 >= 0 && iy1 < HFEAT) ? fy : 0.f;
        const int cx0 = min(max(ix0, 0), WFEAT - 1);
        const int cx1 = min(max(ix1, 0), WFEAT - 1);
        const int cy0 = min(max(iy0, 0), HFEAT - 1);
        const int cy1 = min(max(iy1, 0), HFEAT - 1);
        const float w00 = aw * wy0 * wx0, w01 = aw * wy0 * wx1;
        const float w10 = aw * wy1 * wx0, w11 = aw * wy1 * wx1;
        const s8v v00 = *(const s8v*)(vb + (size_t)(cy0 * WFEAT + cx0) * HDIM);
        const s8v v01 = *(const s8v*)(vb + (size_t)(cy0 * WFEAT + cx1) * HDIM);
        const s8v v10 = *(const s8v*)(vb + (size_t)(cy1 * WFEAT + cx0) * HDIM);
        const s8v v11 = *(const s8v*)(vb + (size_t)(cy1 * WFEAT + cx1) * HDIM);
        #pragma unroll
        for (int k = 0; k < 8; k++) {
            acc[k] += w00 * bf2f_s(v00[k]) + w01 * bf2f_s(v01[k])
                    + w10 * bf2f_s(v10[k]) + w11 * bf2f_s(v11[k]);
        }
    }

    s8v o;
    #pragma unroll
    for (int k = 0; k < 8; k++) o[k] = (short)f2bf(acc[k]);
    *(s8v*)(out + (size_t)row * E_DIM + h * HDIM + j * 8) = o;
}

// ---------------------------------------------------------------------------
extern "C" void kernel_launch(void* const* d_in, const int* in_sizes, int n_in,
                              void* d_out, int out_size, void* d_ws, size_t ws_size,
                              hipStream_t stream) {
    (void)in_sizes; (void)n_in; (void)out_size; (void)ws_size;

    const float* query  = (const float*)d_in[0];
    const float* refp   = (const float*)d_in[1];
    const float* feat   = (const float*)d_in[2];
    const float* ln_q_w = (const float*)d_in[5];
    const float* ln_q_b = (const float*)d_in[6];
    const float* ln_f_w = (const float*)d_in[7];
    const float* ln_f_b = (const float*)d_in[8];
    const float* W_val  = (const float*)d_in[9];
    const float* b_val  = (const float*)d_in[10];
    const float* W_off  = (const float*)d_in[11];
    const float* b_off  = (const float*)d_in[12];
    const float* W_attn = (const float*)d_in[13];
    const float* b_attn = (const float*)d_in[14];
    const float* W_out  = (const float*)d_in[15];
    const float* b_out  = (const float*)d_in[16];
    const float* gamma  = (const float*)d_in[17];
    float* out = (float*)d_out;

    const int MQ = BB * NQS;   // 16384
    const int MV = BB * NVS;   // 36864

    // Workspace layout (bytes)
    char* ws = (char*)d_ws;
    float*          q_stats = (float*)(ws + 0);                   //     131,072
    unsigned short* qbf     = (unsigned short*)(ws + 131072);     //  25,165,824
    unsigned short* fbf     = (unsigned short*)(ws + 25296896);   //  56,623,104
    unsigned short* val_bf  = (unsigned short*)(ws + 81920000);   //  56,623,104 (B,H,S,D)
    unsigned short* msda_bf = (unsigned short*)(ws + 138543104);  //  25,165,824
    float*          offattn = (float*)(ws + 163708928);           //   8,388,608
    unsigned short* Wv_t    = (unsigned short*)(ws + 172097536);  //   1,179,648
    unsigned short* Wo_t    = (unsigned short*)(ws + 173277184);  //   1,179,648
    unsigned short* Wqc_t   = (unsigned short*)(ws + 174456832);  //     196,608
    float*          bcat    = (float*)(ws + 174653440);           //         512

    // 1. LN + bf16 cast (vectorized)
    ln_cast_kernel<true><<<MQ, 192, 0, stream>>>(query, ln_q_w, ln_q_b, qbf, q_stats);
    ln_cast_kernel<false><<<MV, 192, 0, stream>>>(feat, ln_f_w, ln_f_b, fbf, nullptr);

    // 2. weight prep
    transpose_cast_kernel<<<dim3(24, 24), 256, 0, stream>>>(W_val, Wv_t);
    transpose_cast_kernel<<<dim3(24, 24), 256, 0, stream>>>(W_out, Wo_t);
    build_wqc_kernel<<<384, 256, 0, stream>>>(W_off, W_attn, b_off, b_attn, Wqc_t, bcat);

    // 3. value = LN(feat) @ W_value + b_value -> bf16, (B,H,S,D) layout
    mfma_gemm<0><<<dim3(E_DIM / 128, MV / 128), 256, 0, stream>>>(
        fbf, Wv_t, b_val, val_bf, E_DIM, nullptr, nullptr, nullptr, nullptr, nullptr);

    // 4. offsets|attn = LN(q) @ [W_off|W_attn|0] -> fp32 (16384x128)
    mfma_gemm<1><<<dim3(1, MQ / 128), 256, 0, stream>>>(
        qbf, Wqc_t, bcat, offattn, 128, nullptr, nullptr, nullptr, nullptr, nullptr);

    // 5. deformable sampling -> bf16 (row-major B*NQ x 768)
    msda_kernel<<<dim3(NHEAD, MQ / 32), 384, 0, stream>>>(val_bf, offattn, refp, msda_bf);

    // 6. out-proj + fused final residual
    mfma_gemm<2><<<dim3(E_DIM / 128, MQ / 128), 256, 0, stream>>>(
        msda_bf, Wo_t, b_out, out, E_DIM, query, q_stats, ln_q_w, ln_q_b, gamma);
}